// Round 5
// baseline (502.572 us; speedup 1.0000x reference)
//
#include <hip/hip_runtime.h>
#include <hip/hip_bf16.h>

#define B_  64
#define Q_  512
#define C_  128
#define P_  2048
#define G_  256
#define BM  128
#define BN  256
#define BK  64
#define NT  512
#define NTILES (P_ / BK)
#define HALF ((BM + BN) * BK)   // ushorts per LDS buffer (48 KB)

typedef __attribute__((ext_vector_type(8))) short short8;
typedef __attribute__((ext_vector_type(4))) float floatx4;

union FragU { uint4 u; short8 s; };

__device__ __forceinline__ float bf2f(unsigned short h) {
    union { unsigned int i; float f; } v; v.i = ((unsigned int)h) << 16; return v.f;
}
__device__ __forceinline__ unsigned int fbits(float f) {
    union { float f; unsigned int u; } v; v.f = f; return v.u;
}
// f32 -> bf16 bits, round-to-nearest-even (bit trick; inputs finite)
__device__ __forceinline__ unsigned int f2bf(float f) {
    unsigned int u = fbits(f);
    return (u + 0x7FFFu + ((u >> 16) & 1u)) >> 16;
}
__device__ __forceinline__ float splus(float x) {
    // softplus(x) = max(x,0) + log1p(exp(-|x|))
    return fmaxf(x, 0.f) + __logf(1.f + __expf(-fabsf(x)));
}
__device__ __forceinline__ void unpack8(float4 a, float4 b, float* c) {
    c[0] = a.x; c[1] = a.y; c[2] = a.z; c[3] = a.w;
    c[4] = b.x; c[5] = b.y; c[6] = b.z; c[7] = b.w;
}

// Grid (1,4,64)=256 blocks x 512 thr (8 waves: 2m x 4n, wave tile 64x64).
// 1 block/CU. BN=256 => attw read once chip-wide; onehot re-reads L2/L3-absorbed
// (R2 profile: FETCH ~= 1x attw + 1x onehot).
// R2 fix: double-buffered LDS (2x48KB) + ONE barrier per K-tile.
//   {convert t -> buf[t&1]; issue loads t+1; barrier; MFMA t}
// Reg-destination loads stay in flight across the barrier + MFMA (T14);
// convert(t+2) rewrites buf[t&1] one barrier after MFMA(t) -- safe.
__global__ __launch_bounds__(NT, 2)
void fused_cost_kernel(const float* __restrict__ logits,
                       const float* __restrict__ attw,
                       const float* __restrict__ onehot,
                       const int* __restrict__ ids,
                       float* __restrict__ out)
{
    __shared__ unsigned short smem[2 * HALF];  // buf0 | buf1, front reused as Lg
    __shared__ float spq[BM];
    __shared__ int idt[BN];
    __shared__ int sflags;

    const int tid = threadIdx.x;
    const int l   = tid & 63;
    const int w   = tid >> 6;     // 0..7
    const int wm  = w & 1;
    const int wn  = w >> 1;       // 0..3
    const int lm  = l & 15;
    const int lk  = l >> 4;       // 0..3

    const int nb = blockIdx.x * BN;   // always 0 (G_/BN == 1)
    const int mb = blockIdx.y * BM;
    const int b  = blockIdx.z;

    if (tid < BM) spq[tid] = 0.f;
    if (tid == 0) sflags = 0;
    __syncthreads();
    // ids int64-vs-int32 probe: odd words of first 128 entries all 0 iff int64
    // (values in [0,C)). Words [0,256) in bounds under both layouts.
    if (tid < 128) { if (ids[2 * tid + 1] != 0) atomicOr(&sflags, 1); }
    __syncthreads();
    const bool ids32 = (sflags & 1) != 0;
    if (tid < BN) {
        const int gidx = b * G_ + nb + tid;
        idt[tid] = ids32 ? ids[gidx] : ids[2 * gidx];
    }

    // ---- staging roles ----
    // A: 2 k-rows x 8 cols per thread (128x64 tile, 16 floats/thread)
    const int mvA = tid & 15;     // col group (8 cols)
    const int kqA = tid >> 4;     // 0..31 -> rows {2kqA, 2kqA+1}
    const int hbA = kqA >> 2;     // 16B k-group 0..7
    const int kdA = kqA & 3;      // dword slot within group
    // B: 4 k-rows x 8 cols per thread (64x256 tile, 32 floats/thread)
    const int mvB = tid & 31;     // col group (8 cols)
    const int kqB = tid >> 5;     // 0..15 -> rows {4kqB .. 4kqB+3}
    const int hbB = kqB >> 1;     // 16B k-group 0..7
    const int sdB = (kqB & 1) * 4;  // ushort offset of dword pair within group

    const float* aBase = attw   + (size_t)b * P_ * Q_ + (size_t)(2 * kqA) * Q_ + (mb + 8 * mvA);
    const float* bBase = onehot + (size_t)b * P_ * G_ + (size_t)(4 * kqB) * G_ + (nb + 8 * mvB);

    float spacc[8] = {0.f, 0.f, 0.f, 0.f, 0.f, 0.f, 0.f, 0.f};
    floatx4 acc[4][4];
    #pragma unroll
    for (int mi = 0; mi < 4; ++mi)
        #pragma unroll
        for (int ni = 0; ni < 4; ++ni)
            acc[mi][ni] = (floatx4){0.f, 0.f, 0.f, 0.f};

    // preload K-tile 0
    float4 rA0 = *(const float4*)(aBase);
    float4 rA1 = *(const float4*)(aBase + 4);
    float4 rA2 = *(const float4*)(aBase + Q_);
    float4 rA3 = *(const float4*)(aBase + Q_ + 4);
    float4 rB0 = *(const float4*)(bBase);
    float4 rB1 = *(const float4*)(bBase + 4);
    float4 rB2 = *(const float4*)(bBase + G_);
    float4 rB3 = *(const float4*)(bBase + G_ + 4);
    float4 rB4 = *(const float4*)(bBase + 2 * G_);
    float4 rB5 = *(const float4*)(bBase + 2 * G_ + 4);
    float4 rB6 = *(const float4*)(bBase + 3 * G_);
    float4 rB7 = *(const float4*)(bBase + 3 * G_ + 4);

    #pragma unroll 2
    for (int t = 0; t < NTILES; ++t) {
        unsigned short* As = smem + (t & 1) * HALF;
        unsigned short* Bs = As + BM * BK;

        // ---- convert + write A (fused softplus), tile t ----
        {
            float c0[8], c1[8];
            unpack8(rA0, rA1, c0);
            unpack8(rA2, rA3, c1);
            #pragma unroll
            for (int j = 0; j < 8; ++j) {
                spacc[j] += splus(c0[j]) + splus(c1[j]);
                const unsigned int d = f2bf(c0[j]) | (f2bf(c1[j]) << 16);
                const int m  = 8 * mvA + j;
                const int sw = (m + (m >> 3)) & 7;
                *(unsigned int*)(&As[m * BK + ((hbA ^ sw) << 3) + 2 * kdA]) = d;
            }
        }
        // ---- convert + write B (onehot is exactly 0/1: truncation pack) ----
        {
            float c0[8], c1[8], c2[8], c3[8];
            unpack8(rB0, rB1, c0);
            unpack8(rB2, rB3, c1);
            unpack8(rB4, rB5, c2);
            unpack8(rB6, rB7, c3);
            #pragma unroll
            for (int j = 0; j < 8; ++j) {
                uint2 dv;
                dv.x = (fbits(c0[j]) >> 16) | (fbits(c1[j]) & 0xFFFF0000u);
                dv.y = (fbits(c2[j]) >> 16) | (fbits(c3[j]) & 0xFFFF0000u);
                const int n  = 8 * mvB + j;
                const int sw = (n + (n >> 3)) & 7;
                *(uint2*)(&Bs[n * BK + ((hbB ^ sw) << 3) + sdB]) = dv;
            }
        }
        // ---- issue loads for tile t+1 (in flight across barrier + MFMA) ----
        if (t + 1 < NTILES) {
            const float* an = aBase + (size_t)(t + 1) * BK * Q_;
            const float* bn = bBase + (size_t)(t + 1) * BK * G_;
            rA0 = *(const float4*)(an);
            rA1 = *(const float4*)(an + 4);
            rA2 = *(const float4*)(an + Q_);
            rA3 = *(const float4*)(an + Q_ + 4);
            rB0 = *(const float4*)(bn);
            rB1 = *(const float4*)(bn + 4);
            rB2 = *(const float4*)(bn + G_);
            rB3 = *(const float4*)(bn + G_ + 4);
            rB4 = *(const float4*)(bn + 2 * G_);
            rB5 = *(const float4*)(bn + 2 * G_ + 4);
            rB6 = *(const float4*)(bn + 3 * G_);
            rB7 = *(const float4*)(bn + 3 * G_ + 4);
        }
        __builtin_amdgcn_sched_barrier(0);   // pin load issue before the barrier
        __syncthreads();

        // ---- MFMA tile t: 2 k-steps of 32; wave tile 64x64 = 4x4 frags ----
        #pragma unroll
        for (int s = 0; s < 2; ++s) {
            FragU a4[4], b4[4];
            #pragma unroll
            for (int mi = 0; mi < 4; ++mi) {
                const int m  = 64 * wm + 16 * mi + lm;
                const int sw = (m + (m >> 3)) & 7;
                a4[mi].u = *(const uint4*)(&As[m * BK + (((4 * s + lk) ^ sw) << 3)]);
            }
            #pragma unroll
            for (int ni = 0; ni < 4; ++ni) {
                const int n  = 64 * wn + 16 * ni + lm;
                const int sw = (n + (n >> 3)) & 7;
                b4[ni].u = *(const uint4*)(&Bs[n * BK + (((4 * s + lk) ^ sw) << 3)]);
            }
            #pragma unroll
            for (int mi = 0; mi < 4; ++mi)
                #pragma unroll
                for (int ni = 0; ni < 4; ++ni)
                    acc[mi][ni] = __builtin_amdgcn_mfma_f32_16x16x32_bf16(
                        a4[mi].s, b4[ni].s, acc[mi][ni], 0, 0, 0);
        }
    }

    // ---- merge sp_g partials ----
    #pragma unroll
    for (int j = 0; j < 8; ++j)
        atomicAdd(&spq[8 * mvA + j], spacc[j] * (1.0f / P_));

    __syncthreads();   // all MFMA LDS reads done; smem front reusable as Lg

    // ---- logits pass: stage Lg[128 x C_] bf16 into smem + sp_a row sums ----
    {
        const int q  = tid >> 2;
        const int qt = tid & 3;     // 32 floats each
        const float4* src = (const float4*)(logits + ((size_t)b * Q_ + (mb + q)) * C_ + 32 * qt);
        uint2* dst = (uint2*)(&smem[q * C_ + 32 * qt]);
        float ssum = 0.f;
        #pragma unroll
        for (int i = 0; i < 8; ++i) {
            float4 t = src[i];
            ssum += splus(t.x) + splus(t.y) + splus(t.z) + splus(t.w);
            uint2 dv;
            dv.x = f2bf(t.x) | (f2bf(t.y) << 16);
            dv.y = f2bf(t.z) | (f2bf(t.w) << 16);
            dst[i] = dv;
        }
        atomicAdd(&spq[q], ssum * (1.0f / C_));
    }
    __syncthreads();

    // ---- epilogue: cost = spq[q] - acc/P - Lg[q][ids[g]]/C ----
    float* outp = out + ((size_t)b * Q_ + mb) * G_ + nb;
    #pragma unroll
    for (int mi = 0; mi < 4; ++mi) {
        const int q0 = 64 * wm + 16 * mi + 4 * lk;
        #pragma unroll
        for (int ni = 0; ni < 4; ++ni) {
            const int g   = 64 * wn + 16 * ni + lm;   // C/D: col = lane&15 (m89)
            const int cid = idt[g];
            #pragma unroll
            for (int r = 0; r < 4; ++r) {
                const int q = q0 + r;                 // C/D: row = 4*(lane>>4)+reg
                const float val = spq[q]
                                - acc[mi][ni][r] * (1.0f / P_)
                                - bf2f(smem[q * C_ + cid]) * (1.0f / C_);
                outp[(size_t)q * G_ + g] = val;
            }
        }
    }
}

extern "C" void kernel_launch(void* const* d_in, const int* in_sizes, int n_in,
                              void* d_out, int out_size, void* d_ws, size_t ws_size,
                              hipStream_t stream) {
    const float* logits = (const float*)d_in[0];  // [B,Q,C] f32
    const float* attw   = (const float*)d_in[1];  // [B,P,Q] f32
    const float* onehot = (const float*)d_in[2];  // [B,P,G] f32
    const int*   ids    = (const int*)d_in[3];    // [B,G] int32/int64 (probed)
    float*       out    = (float*)d_out;          // [B,Q,G] f32

    dim3 grid(G_ / BN, Q_ / BM, B_);
    hipLaunchKernelGGL(fused_cost_kernel, grid, dim3(NT), 0, stream,
                       logits, attw, onehot, ids, out);
}

// Round 6
// 474.614 us; speedup vs baseline: 1.0589x; 1.0589x over previous
//
#include <hip/hip_runtime.h>
#include <hip/hip_bf16.h>

#define B_  64
#define Q_  512
#define C_  128
#define P_  2048
#define G_  256
#define BM  128
#define BN  256
#define BK  64
#define NT  512
#define NTILES (P_ / BK)
#define HALF ((BM + BN) * BK)   // ushorts per LDS buffer (48 KB)

typedef __attribute__((ext_vector_type(8))) short short8;
typedef __attribute__((ext_vector_type(4))) float floatx4;

union FragU { uint4 u; short8 s; };

__device__ __forceinline__ float bf2f(unsigned short h) {
    union { unsigned int i; float f; } v; v.i = ((unsigned int)h) << 16; return v.f;
}
__device__ __forceinline__ unsigned int fbits(float f) {
    union { float f; unsigned int u; } v; v.f = f; return v.u;
}
// f32 -> bf16 bits, round-to-nearest-even (bit trick; inputs finite)
__device__ __forceinline__ unsigned int f2bf(float f) {
    unsigned int u = fbits(f);
    return (u + 0x7FFFu + ((u >> 16) & 1u)) >> 16;
}
__device__ __forceinline__ float splus(float x) {
    // softplus(x) = max(x,0) + log1p(exp(-|x|))
    return fmaxf(x, 0.f) + __logf(1.f + __expf(-fabsf(x)));
}
__device__ __forceinline__ void unpack8(float4 a, float4 b, float* c) {
    c[0] = a.x; c[1] = a.y; c[2] = a.z; c[3] = a.w;
    c[4] = b.x; c[5] = b.y; c[6] = b.z; c[7] = b.w;
}

// Raw workgroup barrier draining ONLY LDS (lgkmcnt), NOT global loads (vmcnt).
// __syncthreads() would emit s_waitcnt vmcnt(0) and drain the register
// prefetch every iteration (R5 post-mortem: that drain is the bottleneck).
__device__ __forceinline__ void barrier_lds_only() {
    asm volatile("s_waitcnt lgkmcnt(0)" ::: "memory");  // ds_writes visible
    __builtin_amdgcn_s_barrier();
    asm volatile("" ::: "memory");                      // no ds_read hoist
}

// Grid (1,4,64)=256 blocks x 512 thr (8 waves: 2m x 4n, wave tile 64x64).
// BN=256 => attw read once chip-wide; onehot re-reads L2/L3-absorbed.
// Double-buffered LDS (2x48KB), ONE raw barrier per K-tile:
//   {convert t -> buf[t&1]; issue reg-loads t+1; lgkm-only barrier; MFMA t}
// Reg-destination prefetch stays in flight across barrier + MFMA (T4/T14);
// convert(t+2) rewrites buf[t&1] one barrier after MFMA(t) -- WAR safe.
__global__ __launch_bounds__(NT, 2)
void fused_cost_kernel(const float* __restrict__ logits,
                       const float* __restrict__ attw,
                       const float* __restrict__ onehot,
                       const int* __restrict__ ids,
                       float* __restrict__ out)
{
    __shared__ unsigned short smem[2 * HALF];  // buf0 | buf1, front reused as Lg
    __shared__ float spq[BM];
    __shared__ int idt[BN];
    __shared__ int sflags;

    const int tid = threadIdx.x;
    const int l   = tid & 63;
    const int w   = tid >> 6;     // 0..7
    const int wm  = w & 1;
    const int wn  = w >> 1;       // 0..3
    const int lm  = l & 15;
    const int lk  = l >> 4;       // 0..3

    const int nb = blockIdx.x * BN;   // always 0 (G_/BN == 1)
    const int mb = blockIdx.y * BM;
    const int b  = blockIdx.z;

    if (tid < BM) spq[tid] = 0.f;
    if (tid == 0) sflags = 0;
    __syncthreads();
    // ids int64-vs-int32 probe: odd words of first 128 entries all 0 iff int64
    // (values in [0,C)). Words [0,256) in bounds under both layouts.
    if (tid < 128) { if (ids[2 * tid + 1] != 0) atomicOr(&sflags, 1); }
    __syncthreads();
    const bool ids32 = (sflags & 1) != 0;
    if (tid < BN) {
        const int gidx = b * G_ + nb + tid;
        idt[tid] = ids32 ? ids[gidx] : ids[2 * gidx];
    }

    // ---- staging roles ----
    // A: 2 k-rows x 8 cols per thread (128x64 tile, 16 floats/thread)
    const int mvA = tid & 15;     // col group (8 cols)
    const int kqA = tid >> 4;     // 0..31 -> rows {2kqA, 2kqA+1}
    const int hbA = kqA >> 2;     // 16B k-group 0..7
    const int kdA = kqA & 3;      // dword slot within group
    // B: 4 k-rows x 8 cols per thread (64x256 tile, 32 floats/thread)
    const int mvB = tid & 31;     // col group (8 cols)
    const int kqB = tid >> 5;     // 0..15 -> rows {4kqB .. 4kqB+3}
    const int hbB = kqB >> 1;     // 16B k-group 0..7
    const int sdB = (kqB & 1) * 4;  // ushort offset of dword pair within group

    const float* aBase = attw   + (size_t)b * P_ * Q_ + (size_t)(2 * kqA) * Q_ + (mb + 8 * mvA);
    const float* bBase = onehot + (size_t)b * P_ * G_ + (size_t)(4 * kqB) * G_ + (nb + 8 * mvB);

    float spacc[8] = {0.f, 0.f, 0.f, 0.f, 0.f, 0.f, 0.f, 0.f};
    floatx4 acc[4][4];
    #pragma unroll
    for (int mi = 0; mi < 4; ++mi)
        #pragma unroll
        for (int ni = 0; ni < 4; ++ni)
            acc[mi][ni] = (floatx4){0.f, 0.f, 0.f, 0.f};

    // preload K-tile 0
    float4 rA0 = *(const float4*)(aBase);
    float4 rA1 = *(const float4*)(aBase + 4);
    float4 rA2 = *(const float4*)(aBase + Q_);
    float4 rA3 = *(const float4*)(aBase + Q_ + 4);
    float4 rB0 = *(const float4*)(bBase);
    float4 rB1 = *(const float4*)(bBase + 4);
    float4 rB2 = *(const float4*)(bBase + G_);
    float4 rB3 = *(const float4*)(bBase + G_ + 4);
    float4 rB4 = *(const float4*)(bBase + 2 * G_);
    float4 rB5 = *(const float4*)(bBase + 2 * G_ + 4);
    float4 rB6 = *(const float4*)(bBase + 3 * G_);
    float4 rB7 = *(const float4*)(bBase + 3 * G_ + 4);

    #pragma unroll 2
    for (int t = 0; t < NTILES; ++t) {
        unsigned short* As = smem + (t & 1) * HALF;
        unsigned short* Bs = As + BM * BK;

        // ---- convert + write A (fused softplus), tile t ----
        {
            float c0[8], c1[8];
            unpack8(rA0, rA1, c0);
            unpack8(rA2, rA3, c1);
            #pragma unroll
            for (int j = 0; j < 8; ++j) {
                spacc[j] += splus(c0[j]) + splus(c1[j]);
                const unsigned int d = f2bf(c0[j]) | (f2bf(c1[j]) << 16);
                const int m  = 8 * mvA + j;
                const int sw = (m + (m >> 3)) & 7;
                *(unsigned int*)(&As[m * BK + ((hbA ^ sw) << 3) + 2 * kdA]) = d;
            }
        }
        // ---- convert + write B (onehot is exactly 0/1: truncation pack) ----
        {
            float c0[8], c1[8], c2[8], c3[8];
            unpack8(rB0, rB1, c0);
            unpack8(rB2, rB3, c1);
            unpack8(rB4, rB5, c2);
            unpack8(rB6, rB7, c3);
            #pragma unroll
            for (int j = 0; j < 8; ++j) {
                uint2 dv;
                dv.x = (fbits(c0[j]) >> 16) | (fbits(c1[j]) & 0xFFFF0000u);
                dv.y = (fbits(c2[j]) >> 16) | (fbits(c3[j]) & 0xFFFF0000u);
                const int n  = 8 * mvB + j;
                const int sw = (n + (n >> 3)) & 7;
                *(uint2*)(&Bs[n * BK + ((hbB ^ sw) << 3) + sdB]) = dv;
            }
        }
        // ---- issue reg-loads for tile t+1 (stay in flight across barrier) ----
        if (t + 1 < NTILES) {
            const float* an = aBase + (size_t)(t + 1) * BK * Q_;
            const float* bn = bBase + (size_t)(t + 1) * BK * G_;
            rA0 = *(const float4*)(an);
            rA1 = *(const float4*)(an + 4);
            rA2 = *(const float4*)(an + Q_);
            rA3 = *(const float4*)(an + Q_ + 4);
            rB0 = *(const float4*)(bn);
            rB1 = *(const float4*)(bn + 4);
            rB2 = *(const float4*)(bn + G_);
            rB3 = *(const float4*)(bn + G_ + 4);
            rB4 = *(const float4*)(bn + 2 * G_);
            rB5 = *(const float4*)(bn + 2 * G_ + 4);
            rB6 = *(const float4*)(bn + 3 * G_);
            rB7 = *(const float4*)(bn + 3 * G_ + 4);
        }
        barrier_lds_only();   // lgkmcnt(0) + s_barrier; vmcnt NOT drained

        // ---- MFMA tile t: 2 k-steps of 32; wave tile 64x64 = 4x4 frags ----
        #pragma unroll
        for (int s = 0; s < 2; ++s) {
            FragU a4[4], b4[4];
            #pragma unroll
            for (int mi = 0; mi < 4; ++mi) {
                const int m  = 64 * wm + 16 * mi + lm;
                const int sw = (m + (m >> 3)) & 7;
                a4[mi].u = *(const uint4*)(&As[m * BK + (((4 * s + lk) ^ sw) << 3)]);
            }
            #pragma unroll
            for (int ni = 0; ni < 4; ++ni) {
                const int n  = 64 * wn + 16 * ni + lm;
                const int sw = (n + (n >> 3)) & 7;
                b4[ni].u = *(const uint4*)(&Bs[n * BK + (((4 * s + lk) ^ sw) << 3)]);
            }
            #pragma unroll
            for (int mi = 0; mi < 4; ++mi)
                #pragma unroll
                for (int ni = 0; ni < 4; ++ni)
                    acc[mi][ni] = __builtin_amdgcn_mfma_f32_16x16x32_bf16(
                        a4[mi].s, b4[ni].s, acc[mi][ni], 0, 0, 0);
        }
    }

    // ---- merge sp_g partials ----
    #pragma unroll
    for (int j = 0; j < 8; ++j)
        atomicAdd(&spq[8 * mvA + j], spacc[j] * (1.0f / P_));

    __syncthreads();   // full drain OK here (once); smem front reusable as Lg

    // ---- logits pass: stage Lg[128 x C_] bf16 into smem + sp_a row sums ----
    {
        const int q  = tid >> 2;
        const int qt = tid & 3;     // 32 floats each
        const float4* src = (const float4*)(logits + ((size_t)b * Q_ + (mb + q)) * C_ + 32 * qt);
        uint2* dst = (uint2*)(&smem[q * C_ + 32 * qt]);
        float ssum = 0.f;
        #pragma unroll
        for (int i = 0; i < 8; ++i) {
            float4 t = src[i];
            ssum += splus(t.x) + splus(t.y) + splus(t.z) + splus(t.w);
            uint2 dv;
            dv.x = f2bf(t.x) | (f2bf(t.y) << 16);
            dv.y = f2bf(t.z) | (f2bf(t.w) << 16);
            dst[i] = dv;
        }
        atomicAdd(&spq[q], ssum * (1.0f / C_));
    }
    __syncthreads();

    // ---- epilogue: cost = spq[q] - acc/P - Lg[q][ids[g]]/C ----
    float* outp = out + ((size_t)b * Q_ + mb) * G_ + nb;
    #pragma unroll
    for (int mi = 0; mi < 4; ++mi) {
        const int q0 = 64 * wm + 16 * mi + 4 * lk;
        #pragma unroll
        for (int ni = 0; ni < 4; ++ni) {
            const int g   = 64 * wn + 16 * ni + lm;   // C/D: col = lane&15 (m89)
            const int cid = idt[g];
            #pragma unroll
            for (int r = 0; r < 4; ++r) {
                const int q = q0 + r;                 // C/D: row = 4*(lane>>4)+reg
                const float val = spq[q]
                                - acc[mi][ni][r] * (1.0f / P_)
                                - bf2f(smem[q * C_ + cid]) * (1.0f / C_);
                outp[(size_t)q * G_ + g] = val;
            }
        }
    }
}

extern "C" void kernel_launch(void* const* d_in, const int* in_sizes, int n_in,
                              void* d_out, int out_size, void* d_ws, size_t ws_size,
                              hipStream_t stream) {
    const float* logits = (const float*)d_in[0];  // [B,Q,C] f32
    const float* attw   = (const float*)d_in[1];  // [B,P,Q] f32
    const float* onehot = (const float*)d_in[2];  // [B,P,G] f32
    const int*   ids    = (const int*)d_in[3];    // [B,G] int32/int64 (probed)
    float*       out    = (float*)d_out;          // [B,Q,G] f32

    dim3 grid(G_ / BN, Q_ / BM, B_);
    hipLaunchKernelGGL(fused_cost_kernel, grid, dim3(NT), 0, stream,
                       logits, attw, onehot, ids, out);
}